// Round 8
// baseline (718.611 us; speedup 1.0000x reference)
//
#include <hip/hip_runtime.h>
#include <hip/hip_fp16.h>

#define LDIM 50
#define MBIN 262144
#define ODIM 155
#define VOCABSZ 100

// ---- workspace layout (produced by precompute_kernel) ----
// half-indexed (from (__half*)ws), occupying float [0..20000):
#define H_T   0        // 30000 halves : T[s][v][d] fp16 (s=0 pe-slot, b_pred folded; s=1..5 ve-slots)
#define H_PE  30000    // 5000 halves  : pe fp16
#define H_VE  35000    // 5000 halves  : ve fp16
// float-indexed:
#define F_LG  20000    // 300 : attention logits fp32 [0..99]=pe, [100..199]=ve, [200..299]=oe
#define F_TB  20304    // 5000 : (oe @ W_bin[50:100] + b_bin) fp32  (read from GLOBAL, L2-resident)

// ---- static LDS: fp16 tables + fp32 logits = 81216 B -> 2 blocks/CU target ----
// ldsh halves [0..40000) = T|pe|ve ; ldsf floats [20000..20300) = lg
// phase-3 transpose overlays ldsf[0..16896) (tables dead by then)
#define LDS_FLOATS 20304

// ---------------------------------------------------------------------------
// Precompute vocab-indexed tables (trivial cost)
// ---------------------------------------------------------------------------
__global__ __launch_bounds__(64) void precompute_kernel(
    const float* __restrict__ pe, const float* __restrict__ ve, const float* __restrict__ oe,
    const float* __restrict__ W_pred, const float* __restrict__ b_pred,
    const float* __restrict__ W_bin, const float* __restrict__ b_bin,
    const float* __restrict__ W_att, const float* __restrict__ b_att,
    float* __restrict__ ws)
{
    __half* wsh = (__half*)ws;
    const int bid = blockIdx.x;
    const int t = threadIdx.x;
    if (bid < 600) {                    // T tables (fp16)
        const int s = bid / VOCABSZ, v = bid % VOCABSZ;
        if (t < LDIM) {
            const float* E = (s == 0) ? pe : ve;
            float acc = (s == 0) ? b_pred[t] : 0.0f;
            for (int e = 0; e < LDIM; ++e)
                acc += E[v*LDIM + e] * W_pred[(s*LDIM + e)*LDIM + t];
            wsh[H_T + (s*VOCABSZ + v)*LDIM + t] = __float2half_rn(acc);
        }
    } else if (bid < 700) {             // Tb = oe @ W_bin[50:100] + b_bin (fp32)
        const int v = bid - 600;
        if (t < LDIM) {
            float acc = b_bin[t];
            for (int e = 0; e < LDIM; ++e)
                acc += oe[v*LDIM + e] * W_bin[(LDIM + e)*LDIM + t];
            ws[F_TB + v*LDIM + t] = acc;
        }
    } else if (bid < 800) {             // pe -> fp16
        const int v = bid - 700;
        if (t < LDIM) wsh[H_PE + v*LDIM + t] = __float2half_rn(pe[v*LDIM + t]);
    } else if (bid < 900) {             // ve -> fp16
        const int v = bid - 800;
        if (t < LDIM) wsh[H_VE + v*LDIM + t] = __float2half_rn(ve[v*LDIM + t]);
    } else {                            // attention logits (fp32)
        const int g = (bid - 900)*64 + t;
        if (g < 300) {
            const int which = g / VOCABSZ, v = g % VOCABSZ;
            const float* E = (which == 0) ? pe : ((which == 1) ? ve : oe);
            float acc = b_att[0];
            for (int e = 0; e < LDIM; ++e)
                acc += E[v*LDIM + e] * W_att[e];
            ws[F_LG + g] = acc;
        }
    }
}

// ---------------------------------------------------------------------------
// Recompute h[2i],h[2i+1] of a predicate node from fp16 LDS tables.
// Pure function of (i, ids, softmax scalars) — used by all 3 passes.
// ---------------------------------------------------------------------------
__device__ __forceinline__ float2 node_h_i(
    int i, int p, const int* __restrict__ v,
    float e0, const float* __restrict__ ek, float inv,
    const __half* __restrict__ ldsh)
{
    const __half2* T2  = (const __half2*)(ldsh + H_T);
    const __half2* pe2 = (const __half2*)(ldsh + H_PE);
    const __half2* ve2 = (const __half2*)(ldsh + H_VE);
    float2 lin = __half22float2(T2[p*(LDIM/2) + i]);
    float2 pv  = __half22float2(pe2[p*(LDIM/2) + i]);
    float nx = e0*pv.x, ny = e0*pv.y;
#pragma unroll
    for (int s = 0; s < 5; ++s) {
        float2 a = __half22float2(T2[((s+1)*VOCABSZ + v[s])*(LDIM/2) + i]);
        float2 b = __half22float2(ve2[v[s]*(LDIM/2) + i]);
        lin.x += a.x; lin.y += a.y;
        nx += ek[s]*b.x; ny += ek[s]*b.y;
    }
    return make_float2(fmaxf(lin.x, 0.0f) + nx*inv,
                       fmaxf(lin.y, 0.0f) + ny*inv);
}

// ---------------------------------------------------------------------------
// Fused kernel: one thread per binary node; 512-thr; 81216 B static LDS.
// 3-pass streaming: (1) logit pass (live ~30), (2) stream pass consuming h
// into the SINGLE hot accumulator lin2[50] (live ~90), (3) h_bin pass
// recomputing hA/hB per-dim for the attention term (no num[] array).
// No phase has >~95 live floats -> no spills at the immovable 128-VGPR
// allocation -> tests whether spill-free + 81KB LDS unlocks 2 blocks/CU.
// ---------------------------------------------------------------------------
__global__ __launch_bounds__(512)
void fused_kernel(
    const float* __restrict__ oe,
    const float* __restrict__ W_bin,
    const float* __restrict__ W_un, const float* __restrict__ b_un,
    const float* __restrict__ W_univ, const float* __restrict__ b_univ,
    const float* __restrict__ W_att, const float* __restrict__ b_att,
    const float* __restrict__ W_fin, const float* __restrict__ b_fin,
    const int* __restrict__ pred_ids, const int* __restrict__ var_ids,
    const int* __restrict__ op_ids,
    const float* __restrict__ ws, float* __restrict__ out)
{
    __shared__ float ldsf[LDS_FLOATS];          // 81216 B
    __half* ldsh = (__half*)ldsf;
    const float* lgl = ldsf + F_LG;             // fp32 logits in LDS
    const int tid = threadIdx.x;
    const int j = blockIdx.x * 512 + tid;

    // ---- stage fp16 tables (80000 B) + fp32 logits into LDS ----
    {
        const uint4* src = (const uint4*)ws;    // halves [0..40000) = 5000 uint4
        uint4* dst = (uint4*)ldsh;
        for (int i = tid; i < 5000; i += 512) dst[i] = src[i];
        if (tid < 300) ldsf[F_LG + tid] = ws[F_LG + tid];
    }
    __syncthreads();

    const float batt = b_att[0];

    // ---- node ids + softmax scalars (persist across all 3 passes) ----
    int vA[5], vB[5];
    const int pA = pred_ids[2*j], pB = pred_ids[2*j+1];
#pragma unroll
    for (int s = 0; s < 5; ++s) { vA[s] = var_ids[(2*j)*5 + s]; vB[s] = var_ids[(2*j+1)*5 + s]; }
    const int op = op_ids[j];

    float ekA[5], ekB[5];
    const float e0A = __expf(lgl[pA]);
    const float e0B = __expf(lgl[pB]);
    float denA = e0A, denB = e0B;
#pragma unroll
    for (int s = 0; s < 5; ++s) {
        ekA[s] = __expf(lgl[VOCABSZ + vA[s]]); denA += ekA[s];
        ekB[s] = __expf(lgl[VOCABSZ + vB[s]]); denB += ekB[s];
    }
    const float invA = 1.0f / denA, invB = 1.0f / denB;

    // ---- pass 1: attention logits (rolled, no h storage) ----
    float lA = batt, lB = batt;
    for (int i = 0; i < LDIM/2; ++i) {
        float2 a = node_h_i(i, pA, vA, e0A, ekA, invA, ldsh);
        float2 b = node_h_i(i, pB, vB, e0B, ekB, invB, ldsh);
        lA += a.x*W_att[2*i] + a.y*W_att[2*i+1];
        lB += b.x*W_att[2*i] + b.y*W_att[2*i+1];
    }
    const float w0 = __expf(lA);
    const float w2 = __expf(lB);
    const float w1 = __expf(lgl[2*VOCABSZ + op]);
    const float inv2 = 1.0f / (w0 + w1 + w2);

    // ---- pass 2: lin2 = hA @ Wbin[0:50] + hB @ Wbin[100:150] (streamed) ----
    float lin2[LDIM];
#pragma unroll
    for (int d = 0; d < LDIM; ++d) lin2[d] = 0.0f;
#pragma unroll
    for (int i = 0; i < LDIM/2; ++i) {
        const float2 a = node_h_i(i, pA, vA, e0A, ekA, invA, ldsh);
        const float* wr0 = W_bin + (2*i)*LDIM;               // wave-uniform rows
        const float* wr1 = W_bin + (2*i+1)*LDIM;
#pragma unroll
        for (int d = 0; d < LDIM; ++d) lin2[d] += a.x*wr0[d] + a.y*wr1[d];
    }
#pragma unroll
    for (int i = 0; i < LDIM/2; ++i) {
        const float2 b = node_h_i(i, pB, vB, e0B, ekB, invB, ldsh);
        const float* wr0 = W_bin + (2*LDIM + 2*i)*LDIM;
        const float* wr1 = W_bin + (2*LDIM + 2*i+1)*LDIM;
#pragma unroll
        for (int d = 0; d < LDIM; ++d) lin2[d] += b.x*wr0[d] + b.y*wr1[d];
    }

    // ---- pass 3: h_bin = relu(lin2 + Tb[op]) + (w0*hA + w2*hB + w1*oe[op])*inv2
    //      hA/hB recomputed per-dim; Tb/oe rows read fp32 from global (L2-hot)
    float h[LDIM];
    {
        const float2* Tb2 = (const float2*)(ws + F_TB + op*LDIM);
        const float2* oe2 = (const float2*)(oe + op*LDIM);
#pragma unroll
        for (int i = 0; i < LDIM/2; ++i) {
            const float2 a = node_h_i(i, pA, vA, e0A, ekA, invA, ldsh);
            const float2 b = node_h_i(i, pB, vB, e0B, ekB, invB, ldsh);
            const float2 t2 = Tb2[i];
            const float2 o2 = oe2[i];
            h[2*i]   = fmaxf(lin2[2*i]   + t2.x, 0.0f) + (w0*a.x + w2*b.x + w1*o2.x)*inv2;
            h[2*i+1] = fmaxf(lin2[2*i+1] + t2.y, 0.0f) + (w0*a.y + w2*b.y + w1*o2.y)*inv2;
        }
    }

    // ---- h_un = relu(h @ W_un + b_un); h_q = relu(h_un @ W_univ + b_univ) ----
    {
        float acc[LDIM];
#pragma unroll
        for (int d = 0; d < LDIM; ++d) acc[d] = b_un[d];
#pragma unroll
        for (int e = 0; e < LDIM; ++e) {
            const float he = h[e];
            const float* wr = W_un + e*LDIM;
#pragma unroll
            for (int d = 0; d < LDIM; ++d) acc[d] += he * wr[d];
        }
#pragma unroll
        for (int d = 0; d < LDIM; ++d) h[d] = fmaxf(acc[d], 0.0f);
    }
    {
        float acc[LDIM];
#pragma unroll
        for (int d = 0; d < LDIM; ++d) acc[d] = b_univ[d];
#pragma unroll
        for (int e = 0; e < LDIM; ++e) {
            const float he = h[e];
            const float* wr = W_univ + e*LDIM;
#pragma unroll
            for (int d = 0; d < LDIM; ++d) acc[d] += he * wr[d];
        }
#pragma unroll
        for (int d = 0; d < LDIM; ++d) h[d] = fmaxf(acc[d], 0.0f);
    }

    __syncthreads();   // all table reads done: phase-3 transpose overlay is safe

    // ---- phase 3: out row = h @ W_fin + b_fin, LDS-transposed coalesced stores
    //      (per-wave buffer overlaying dead tables; 8 waves * 2112 = 16896 <= 20304)
    const int wave = tid >> 6, lane = tid & 63;
    float* sw = ldsf + wave * (64*33);
    const int rowbase = blockIdx.x*512 + wave*64;
    for (int c = 0; c < 5; ++c) {
        float acc[31];
        const int obase = c * 31;
#pragma unroll
        for (int o = 0; o < 31; ++o) acc[o] = b_fin[obase + o];
#pragma unroll
        for (int d = 0; d < LDIM; ++d) {
            const float hq = h[d];
            const float* wr = W_fin + d*ODIM + obase;
#pragma unroll
            for (int o = 0; o < 31; ++o) acc[o] += hq * wr[o];
        }
#pragma unroll
        for (int o = 0; o < 31; ++o) sw[lane*33 + o] = acc[o];
        float* gb = out + (size_t)rowbase * ODIM + obase;
#pragma unroll
        for (int it = 0; it < 31; ++it) {
            const int f = it*64 + lane;
            const int row = f / 31;
            const int col = f - row*31;
            gb[row*ODIM + col] = sw[row*33 + col];
        }
    }
}

// ---------------------------------------------------------------------------
extern "C" void kernel_launch(void* const* d_in, const int* in_sizes, int n_in,
                              void* d_out, int out_size, void* d_ws, size_t ws_size,
                              hipStream_t stream) {
    const float* pe     = (const float*)d_in[0];
    const float* ve     = (const float*)d_in[1];
    const float* oe     = (const float*)d_in[2];
    const float* W_pred = (const float*)d_in[3];
    const float* b_pred = (const float*)d_in[4];
    const float* W_bin  = (const float*)d_in[5];
    const float* b_bin  = (const float*)d_in[6];
    const float* W_un   = (const float*)d_in[7];
    const float* b_un   = (const float*)d_in[8];
    const float* W_univ = (const float*)d_in[9];
    const float* b_univ = (const float*)d_in[10];
    const float* W_att  = (const float*)d_in[11];
    const float* b_att  = (const float*)d_in[12];
    const float* W_fin  = (const float*)d_in[13];
    const float* b_fin  = (const float*)d_in[14];
    const int* pred_ids = (const int*)d_in[15];
    const int* var_ids  = (const int*)d_in[16];
    const int* op_ids   = (const int*)d_in[17];
    float* out = (float*)d_out;
    float* ws  = (float*)d_ws;

    precompute_kernel<<<905, 64, 0, stream>>>(pe, ve, oe, W_pred, b_pred,
                                              W_bin, b_bin, W_att, b_att, ws);
    fused_kernel<<<MBIN/512, 512, 0, stream>>>(oe, W_bin, W_un, b_un,
                                               W_univ, b_univ, W_att, b_att,
                                               W_fin, b_fin, pred_ids, var_ids,
                                               op_ids, ws, out);
}